// Round 1
// 254.066 us; speedup vs baseline: 1.0014x; 1.0014x over previous
//
#include <hip/hip_runtime.h>

#define N_NODES 25600
#define F_IN 400
#define NE 512000
#define NB 64
#define NPG 400
#define EPG 8000
#define BN_EPS 1e-5f

#define S_ROWS 448      // 400 padded to 7*64
#define S_COLS 448      // 400 padded to 7*64 (BK=64 k-loop)
#define S_COLS2 (S_COLS / 2)   // u4-packed row bytes
#define AGG_TILES 7     // 448/64  (M=64 tiles)
#define SB_RPB 112      // adjacency rows per build block (4 blocks/graph)
#define K0PAD 448       // wt0 K padded to 7*64

typedef __attribute__((ext_vector_type(8))) short short8;
typedef __attribute__((ext_vector_type(4))) short short4_t;
typedef __attribute__((ext_vector_type(4))) float floatx4;

__device__ __forceinline__ unsigned short f2bf(float f) {
    unsigned int u = __float_as_uint(f);
    u += 0x7FFF + ((u >> 16) & 1);   // RNE
    return (unsigned short)(u >> 16);
}
__device__ __forceinline__ float bf2f(unsigned short s) {
    return __uint_as_float((unsigned int)s << 16);
}
// exact for integers 0..255 (<=8 mantissa bits)
__device__ __forceinline__ short u8bf(unsigned v) {
    return (short)(__float_as_uint((float)v) >> 16);
}

// ---------------- prep: build u4 adjacency (blocks 0..255) + weight transposes + zero stats ----------------

__global__ __launch_bounds__(256) void prep(const int* __restrict__ src,
                                            const int* __restrict__ dst,
                                            unsigned char* __restrict__ Sb,
                                            const float* __restrict__ wa0, const float* __restrict__ wa1,
                                            const float* __restrict__ wa2, const float* __restrict__ wb0,
                                            const float* __restrict__ wb1, const float* __restrict__ wb2,
                                            unsigned short* __restrict__ t0, unsigned short* __restrict__ t1,
                                            unsigned short* __restrict__ t2, unsigned short* __restrict__ t3,
                                            unsigned short* __restrict__ t4, unsigned short* __restrict__ t5,
                                            float* __restrict__ pstat) {
    __shared__ int cnt32[SB_RPB * NPG / 4];   // 44.8 KB (only used by build blocks)
    int tid = threadIdx.x;
    if (blockIdx.x < 256) {
        int b = blockIdx.x;
        int g = b >> 2, part = b & 3;
        int r0 = part * SB_RPB;
        for (int i = tid; i < SB_RPB * NPG / 4; i += 256) cnt32[i] = 0;
        __syncthreads();
        int ebase = g * EPG, nbase = g * NPG;
        for (int e = tid; e < EPG; e += 256) {
            int d = dst[ebase + e] - nbase;
            int dr = d - r0;
            if ((unsigned)dr < (unsigned)SB_RPB) {
                int s = src[ebase + e] - nbase;
                int idx = dr * NPG + s;
                atomicAdd(&cnt32[idx >> 2], (int)(1u << ((idx & 3) * 8)));
            }
        }
        __syncthreads();
        const unsigned char* cb = (const unsigned char*)cnt32;
        // pack 8 cells -> 4 bytes (u4 nibbles); counts provably < 16
        for (int i = tid; i < SB_RPB * (S_COLS / 8); i += 256) {
            int rr = i / (S_COLS / 8), c8 = (i % (S_COLS / 8)) * 8;
            int R = r0 + rr;
            unsigned pk = 0;
#pragma unroll
            for (int j = 0; j < 8; ++j) {
                int c = c8 + j;
                unsigned v = 0;
                if (R < NPG && c < NPG) v = (unsigned)cb[rr * NPG + c] + (c == R ? 1u : 0u);
                pk |= (v & 15u) << (4 * j);
            }
            *(unsigned*)&Sb[((size_t)g * S_ROWS + R) * S_COLS2 + (c8 >> 1)] = pk;
        }
        return;
    }
    // ---- transpose part + zero pstat(6144) and pooled(8192) ----
    int idx = (blockIdx.x - 256) * 256 + tid;
    if (idx < 3 * 2048 + 8192) pstat[idx] = 0.f;
    if (idx < 128 * K0PAD) {
        int n = idx / K0PAD, k = idx - n * K0PAD;
        t0[idx] = (k < 400) ? f2bf(wa0[(size_t)k * 128 + n]) : (unsigned short)0;
        return;
    }
    idx -= 128 * K0PAD;
    if (idx >= 5 * 128 * 128) return;
    int seg = idx >> 14;
    int r = idx & 16383;
    int n = r >> 7, k = r & 127;
    const float* srcs[5] = {wb0, wa1, wb1, wa2, wb2};
    unsigned short* dsts[5] = {t3, t1, t4, t2, t5};
    dsts[seg][r] = f2bf(srcs[seg][(size_t)k * 128 + n]);
}

// ---------------- layer-0 GEMM: tT = ([x | ge | he] @ W0a)^T, bf16 out, M=64 tiles, BK=64 ----------------

__global__ __launch_bounds__(256) void gemm_embed64(const float* __restrict__ A,
                                                    const unsigned short* __restrict__ Wt,
                                                    const float* __restrict__ Wfull,
                                                    const int* __restrict__ gid,
                                                    const float* __restrict__ ge,
                                                    const float* __restrict__ he,
                                                    unsigned short* __restrict__ CtT) {
    __shared__ __align__(16) unsigned short As[64][72];
    __shared__ __align__(16) unsigned short Bs[128][72];
    __shared__ float Wex[4][128];
    int tid = threadIdx.x;
    int m0 = blockIdx.x * 64;
    int wave = tid >> 6, lane = tid & 63;
    int wcol = wave * 32;
    int fm = lane & 15, quad = lane >> 4;

    for (int i = tid; i < 512; i += 256)
        Wex[i >> 7][i & 127] = Wfull[(size_t)(400 + (i >> 7)) * 128 + (i & 127)];

    floatx4 acc[4][2];
#pragma unroll
    for (int rt = 0; rt < 4; ++rt)
#pragma unroll
        for (int ct = 0; ct < 2; ++ct) acc[rt][ct] = (floatx4){0.f, 0.f, 0.f, 0.f};

    const int rA = tid >> 2, kcA = (tid & 3) * 16;    // 64 rows x 64 k fp32, 16/thread
    const int nB = tid >> 1, kcB = (tid & 1) * 32;    // 128 rows x 64 k bf16, 32/thread
    float4 aP0, aP1, aP2, aP3;
    short8 bP0, bP1, bP2, bP3;

    auto loadK = [&](int ks) {
        int k0 = ks * 64;
        int kg = k0 + kcA;
        const float* ar = A + (size_t)(m0 + rA) * F_IN;
        if (kg + 15 < 400) {
            aP0 = *(const float4*)(ar + kg);
            aP1 = *(const float4*)(ar + kg + 4);
            aP2 = *(const float4*)(ar + kg + 8);
            aP3 = *(const float4*)(ar + kg + 12);
        } else {
            float v[16];
#pragma unroll
            for (int j = 0; j < 16; ++j) v[j] = (kg + j < 400) ? ar[kg + j] : 0.f;
            aP0 = (float4){v[0], v[1], v[2], v[3]};
            aP1 = (float4){v[4], v[5], v[6], v[7]};
            aP2 = (float4){v[8], v[9], v[10], v[11]};
            aP3 = (float4){v[12], v[13], v[14], v[15]};
        }
        const unsigned short* wr = Wt + (size_t)nB * K0PAD + k0 + kcB;  // zero-padded: no guard
        bP0 = *(const short8*)wr;
        bP1 = *(const short8*)(wr + 8);
        bP2 = *(const short8*)(wr + 16);
        bP3 = *(const short8*)(wr + 24);
    };

    loadK(0);
    for (int ks = 0; ks < 7; ++ks) {
        {
            short8 s0, s1;
            s0[0] = (short)f2bf(aP0.x); s0[1] = (short)f2bf(aP0.y);
            s0[2] = (short)f2bf(aP0.z); s0[3] = (short)f2bf(aP0.w);
            s0[4] = (short)f2bf(aP1.x); s0[5] = (short)f2bf(aP1.y);
            s0[6] = (short)f2bf(aP1.z); s0[7] = (short)f2bf(aP1.w);
            s1[0] = (short)f2bf(aP2.x); s1[1] = (short)f2bf(aP2.y);
            s1[2] = (short)f2bf(aP2.z); s1[3] = (short)f2bf(aP2.w);
            s1[4] = (short)f2bf(aP3.x); s1[5] = (short)f2bf(aP3.y);
            s1[6] = (short)f2bf(aP3.z); s1[7] = (short)f2bf(aP3.w);
            *(short8*)&As[rA][kcA] = s0;
            *(short8*)&As[rA][kcA + 8] = s1;
            *(short8*)&Bs[nB][kcB] = bP0;
            *(short8*)&Bs[nB][kcB + 8] = bP1;
            *(short8*)&Bs[nB][kcB + 16] = bP2;
            *(short8*)&Bs[nB][kcB + 24] = bP3;
        }
        __syncthreads();
        if (ks + 1 < 7) loadK(ks + 1);
#pragma unroll
        for (int k0l = 0; k0l < 64; k0l += 32) {
            short8 af[4], bf[2];
#pragma unroll
            for (int rt = 0; rt < 4; ++rt)
                af[rt] = *(const short8*)&As[rt * 16 + fm][k0l + quad * 8];
#pragma unroll
            for (int ct = 0; ct < 2; ++ct)
                bf[ct] = *(const short8*)&Bs[wcol + ct * 16 + fm][k0l + quad * 8];
#pragma unroll
            for (int rt = 0; rt < 4; ++rt)
#pragma unroll
                for (int ct = 0; ct < 2; ++ct)
                    acc[rt][ct] = __builtin_amdgcn_mfma_f32_16x16x32_bf16(
                        af[rt], bf[ct], acc[rt][ct], 0, 0, 0);
        }
        __syncthreads();
    }

#pragma unroll
    for (int rt = 0; rt < 4; ++rt) {
#pragma unroll
        for (int ct = 0; ct < 2; ++ct) {
            int col = wcol + ct * 16 + fm;
            int row0 = m0 + rt * 16 + quad * 4;
            ushort4 o;
#pragma unroll
            for (int r = 0; r < 4; ++r) {
                int row = row0 + r;
                int gv = gid[row];
                float v = acc[rt][ct][r]
                        + ge[gv * 2] * Wex[0][col] + ge[gv * 2 + 1] * Wex[1][col]
                        + he[(row & 1) * 2] * Wex[2][col] + he[(row & 1) * 2 + 1] * Wex[3][col];
                ((unsigned short*)&o)[r] = f2bf(v);
            }
            *(ushort4*)&CtT[(size_t)col * N_NODES + row0] = o;
        }
    }
}

// ---------------- aggregation: z = (S+I) @ t + bias (bf16 out), atomic BN partials ----------------
// Sb is u4-packed (exact counts); unpack nibbles -> bf16 during staging. M=64 tiles, BK=64, XCD swizzle.

__global__ __launch_bounds__(256) void agg_mfma(const unsigned char* __restrict__ Sb,
                                                const unsigned short* __restrict__ tT,
                                                const float* __restrict__ bias,
                                                unsigned short* __restrict__ z,
                                                float* __restrict__ psumG,
                                                float* __restrict__ psqG) {
    __shared__ __align__(16) unsigned short As[64][72];
    __shared__ __align__(16) unsigned short Bs[128][72];
    __shared__ float sw[4][2][16], qw[4][2][16];
    int tid = threadIdx.x;
    int b = blockIdx.x;
    int g = b & 63;            // XCD-locality: same-g blocks share b%8
    int tile = b >> 6;         // 0..6
    int m0l = tile * 64;
    int node0 = g * NPG;
    int wave = tid >> 6, lane = tid & 63;
    int wcol = wave * 32;
    int fm = lane & 15, quad = lane >> 4;

    floatx4 acc[4][2];
#pragma unroll
    for (int rt = 0; rt < 4; ++rt)
#pragma unroll
        for (int ct = 0; ct < 2; ++ct) acc[rt][ct] = (floatx4){0.f, 0.f, 0.f, 0.f};

    const int rA = tid >> 2, kcA = (tid & 3) * 16;    // 64 rows x 64 k u4, 8 bytes/thread
    const int nB = tid >> 1, kcB = (tid & 1) * 32;    // 128 rows x 64 k bf16
    unsigned long long aP;
    short8 bP0, bP1, bP2, bP3;

    auto loadK = [&](int ks) {
        int k0 = ks * 64;
        aP = *(const unsigned long long*)(Sb + ((size_t)g * S_ROWS + m0l + rA) * S_COLS2 + ((k0 + kcA) >> 1));
        const unsigned short* p = tT + (size_t)nB * N_NODES + node0 + k0 + kcB;
        bP0 = *(const short8*)p;
        bP1 = *(const short8*)(p + 8);
        bP2 = *(const short8*)(p + 16);
        bP3 = *(const short8*)(p + 24);
    };

    loadK(0);
    for (int ks = 0; ks < S_COLS / 64; ++ks) {
        {
            short8 s0, s1;
#pragma unroll
            for (int j = 0; j < 8; ++j) s0[j] = u8bf((unsigned)(aP >> (4 * j)) & 15u);
#pragma unroll
            for (int j = 0; j < 8; ++j) s1[j] = u8bf((unsigned)(aP >> (32 + 4 * j)) & 15u);
            *(short8*)&As[rA][kcA] = s0;
            *(short8*)&As[rA][kcA + 8] = s1;
            *(short8*)&Bs[nB][kcB] = bP0;
            *(short8*)&Bs[nB][kcB + 8] = bP1;
            *(short8*)&Bs[nB][kcB + 16] = bP2;
            *(short8*)&Bs[nB][kcB + 24] = bP3;
        }
        __syncthreads();
        if (ks + 1 < S_COLS / 64) loadK(ks + 1);
#pragma unroll
        for (int k0l = 0; k0l < 64; k0l += 32) {
            short8 af[4], bf[2];
#pragma unroll
            for (int rt = 0; rt < 4; ++rt)
                af[rt] = *(const short8*)&As[rt * 16 + fm][k0l + quad * 8];
#pragma unroll
            for (int ct = 0; ct < 2; ++ct)
                bf[ct] = *(const short8*)&Bs[wcol + ct * 16 + fm][k0l + quad * 8];
#pragma unroll
            for (int rt = 0; rt < 4; ++rt)
#pragma unroll
                for (int ct = 0; ct < 2; ++ct)
                    acc[rt][ct] = __builtin_amdgcn_mfma_f32_16x16x32_bf16(
                        af[rt], bf[ct], acc[rt][ct], 0, 0, 0);
        }
        __syncthreads();
    }

    {
        float scol[2] = {0.f, 0.f}, qcol[2] = {0.f, 0.f};
#pragma unroll
        for (int rt = 0; rt < 4; ++rt) {
#pragma unroll
            for (int ct = 0; ct < 2; ++ct) {
                int col = wcol + ct * 16 + fm;
                float bv = bias[col];
                int rbase = m0l + rt * 16 + quad * 4;
#pragma unroll
                for (int r = 0; r < 4; ++r) {
                    int rloc = rbase + r;
                    if (rloc < NPG) {
                        float v = acc[rt][ct][r] + bv;
                        z[(size_t)(node0 + rloc) * 128 + col] = f2bf(v);
                        scol[ct] += v;
                        qcol[ct] += v * v;
                    }
                }
            }
        }
#pragma unroll
        for (int ct = 0; ct < 2; ++ct) {
            scol[ct] += __shfl_xor(scol[ct], 16);
            scol[ct] += __shfl_xor(scol[ct], 32);
            qcol[ct] += __shfl_xor(qcol[ct], 16);
            qcol[ct] += __shfl_xor(qcol[ct], 32);
        }
        if (lane < 16) {
#pragma unroll
            for (int ct = 0; ct < 2; ++ct) { sw[wave][ct][lane] = scol[ct]; qw[wave][ct][lane] = qcol[ct]; }
        }
    }
    __syncthreads();
    if (tid < 128) {
        int c = tid;
        int wv = c >> 5, ct = (c >> 4) & 1, f = c & 15;
        int bucket = b & 7;
        atomicAdd(&psumG[bucket * 128 + c], sw[wv][ct][f]);
        atomicAdd(&psqG[bucket * 128 + c], qw[wv][ct][f]);
    }
}

// ---------------- fused: BN reduce + h = relu(relu(affine(z)) @ wb + bb) [+ t' = h @ wa_next | pool] ----------------
// M=64 tiles -> 400 blocks; phase-1 BK=64 register-prefetched. As aliased into hs (phase-1 A-tile dead
// before h is written; stride 136 has the same bank profile as 72).
// MODE_FINAL: instead of materializing h, atomically accumulate per-graph pooled sums (fp32).

#define MODE_FUSED 0
#define MODE_FINAL 1

template <int MODE>
__global__ __launch_bounds__(256) void gemm_post64(const unsigned short* __restrict__ z,
                                                   const float* __restrict__ psumG,
                                                   const float* __restrict__ psqG,
                                                   const float* __restrict__ gamma,
                                                   const float* __restrict__ beta,
                                                   const unsigned short* __restrict__ wtb,
                                                   const float* __restrict__ bb,
                                                   const unsigned short* __restrict__ wta_next,
                                                   unsigned short* __restrict__ CtT,
                                                   float* __restrict__ pooled) {
    __shared__ __align__(16) unsigned short Bs[128][72];
    __shared__ __align__(16) unsigned short hs[64][136];   // phase-1 A-tile (cols 0..71) then h (cols 0..127)
    __shared__ float coefs[256];
    int tid = threadIdx.x;
    int m0 = blockIdx.x * 64;
    int wave = tid >> 6, lane = tid & 63;
    int wcol = wave * 32;
    int fm = lane & 15, quad = lane >> 4;

    if (tid < 128) {
        float S = 0.f, Q = 0.f;
#pragma unroll
        for (int b = 0; b < 8; ++b) { S += psumG[b * 128 + tid]; Q += psqG[b * 128 + tid]; }
        float invn = 1.0f / (float)N_NODES;
        float mu = S * invn;
        float var = Q * invn - mu * mu;
        float a = gamma[tid] * rsqrtf(var + BN_EPS);
        coefs[tid] = a;
        coefs[128 + tid] = beta[tid] - a * mu;
    }
    __syncthreads();

    floatx4 acc[4][2];
#pragma unroll
    for (int rt = 0; rt < 4; ++rt)
#pragma unroll
        for (int ct = 0; ct < 2; ++ct) acc[rt][ct] = (floatx4){0.f, 0.f, 0.f, 0.f};

    const int rA = tid >> 2, kcA = (tid & 3) * 16;    // 64 rows x 64 k bf16, 16/thread
    const int nB = tid >> 1, kcB = (tid & 1) * 32;
    short8 aPa, aPb;
    short8 bP0, bP1, bP2, bP3;

    auto loadK1 = [&](int ks) {
        int k0 = ks * 64;
        const unsigned short* zr = &z[(size_t)(m0 + rA) * 128 + k0 + kcA];
        aPa = *(const short8*)zr;
        aPb = *(const short8*)(zr + 8);
        const unsigned short* wr = wtb + (size_t)nB * 128 + k0 + kcB;
        bP0 = *(const short8*)wr;
        bP1 = *(const short8*)(wr + 8);
        bP2 = *(const short8*)(wr + 16);
        bP3 = *(const short8*)(wr + 24);
    };

    // ---- phase 1: relu(affine(z)) @ wb, BK=64 (2 ksteps) ----
    loadK1(0);
    for (int ks = 0; ks < 2; ++ks) {
        {
            int kg = ks * 64 + kcA;
            short8 s0, s1;
#pragma unroll
            for (int j = 0; j < 8; ++j) {
                float v = fmaxf(coefs[kg + j] * bf2f((unsigned short)aPa[j]) + coefs[128 + kg + j], 0.f);
                s0[j] = (short)f2bf(v);
            }
#pragma unroll
            for (int j = 0; j < 8; ++j) {
                float v = fmaxf(coefs[kg + 8 + j] * bf2f((unsigned short)aPb[j]) + coefs[128 + kg + 8 + j], 0.f);
                s1[j] = (short)f2bf(v);
            }
            *(short8*)&hs[rA][kcA] = s0;
            *(short8*)&hs[rA][kcA + 8] = s1;
            *(short8*)&Bs[nB][kcB] = bP0;
            *(short8*)&Bs[nB][kcB + 8] = bP1;
            *(short8*)&Bs[nB][kcB + 16] = bP2;
            *(short8*)&Bs[nB][kcB + 24] = bP3;
        }
        __syncthreads();
        if (ks + 1 < 2) loadK1(ks + 1);
#pragma unroll
        for (int k0l = 0; k0l < 64; k0l += 32) {
            short8 af[4], bf[2];
#pragma unroll
            for (int rt = 0; rt < 4; ++rt)
                af[rt] = *(const short8*)&hs[rt * 16 + fm][k0l + quad * 8];
#pragma unroll
            for (int ct = 0; ct < 2; ++ct)
                bf[ct] = *(const short8*)&Bs[wcol + ct * 16 + fm][k0l + quad * 8];
#pragma unroll
            for (int rt = 0; rt < 4; ++rt)
#pragma unroll
                for (int ct = 0; ct < 2; ++ct)
                    acc[rt][ct] = __builtin_amdgcn_mfma_f32_16x16x32_bf16(
                        af[rt], bf[ct], acc[rt][ct], 0, 0, 0);
        }
        __syncthreads();
    }

    if (MODE == MODE_FINAL) {
        // pool relu(acc+bb) per graph; 4-row runs never cross graph boundary (400 % 4 == 0)
        float rsum[4][2];
#pragma unroll
        for (int rt = 0; rt < 4; ++rt)
#pragma unroll
            for (int ct = 0; ct < 2; ++ct) {
                int col = wcol + ct * 16 + fm;
                float bv = bb[col];
                float s = 0.f;
#pragma unroll
                for (int r = 0; r < 4; ++r) s += fmaxf(acc[rt][ct][r] + bv, 0.f);
                rsum[rt][ct] = s;
            }
        bool uniform = (m0 / NPG) == ((m0 + 63) / NPG);
        if (uniform) {
            int gph = m0 / NPG;
#pragma unroll
            for (int ct = 0; ct < 2; ++ct) {
                float cs = rsum[0][ct] + rsum[1][ct] + rsum[2][ct] + rsum[3][ct];
                cs += __shfl_xor(cs, 16);
                cs += __shfl_xor(cs, 32);
                if (lane < 16) atomicAdd(&pooled[gph * 128 + wcol + ct * 16 + fm], cs);
            }
        } else {
#pragma unroll
            for (int rt = 0; rt < 4; ++rt)
#pragma unroll
                for (int ct = 0; ct < 2; ++ct) {
                    int gph = (m0 + rt * 16 + quad * 4) / NPG;
                    atomicAdd(&pooled[gph * 128 + wcol + ct * 16 + fm], rsum[rt][ct]);
                }
        }
        return;
    }

#pragma unroll
    for (int rt = 0; rt < 4; ++rt)
#pragma unroll
        for (int ct = 0; ct < 2; ++ct) {
            int col = wcol + ct * 16 + fm;
            float bv = bb[col];
            int rbase = rt * 16 + quad * 4;
#pragma unroll
            for (int r = 0; r < 4; ++r)
                hs[rbase + r][col] = f2bf(fmaxf(acc[rt][ct][r] + bv, 0.f));
        }
    __syncthreads();

    // ---- phase 2: t' = h @ wa_next (BK=32 from LDS) ----
#pragma unroll
    for (int rt = 0; rt < 4; ++rt)
#pragma unroll
        for (int ct = 0; ct < 2; ++ct) acc[rt][ct] = (floatx4){0.f, 0.f, 0.f, 0.f};

    const int kcB2 = (tid & 1) * 16;
    for (int ks = 0; ks < 4; ++ks) {
        int k0 = ks * 32;
        {
            const unsigned short* wr = wta_next + (size_t)nB * 128 + k0 + kcB2;
            *(short8*)&Bs[nB][kcB2] = *(const short8*)wr;
            *(short8*)&Bs[nB][kcB2 + 8] = *(const short8*)(wr + 8);
        }
        __syncthreads();
        {
            short8 af[4], bf[2];
#pragma unroll
            for (int rt = 0; rt < 4; ++rt)
                af[rt] = *(const short8*)&hs[rt * 16 + fm][k0 + quad * 8];
#pragma unroll
            for (int ct = 0; ct < 2; ++ct)
                bf[ct] = *(const short8*)&Bs[wcol + ct * 16 + fm][quad * 8];
#pragma unroll
            for (int rt = 0; rt < 4; ++rt)
#pragma unroll
                for (int ct = 0; ct < 2; ++ct)
                    acc[rt][ct] = __builtin_amdgcn_mfma_f32_16x16x32_bf16(
                        af[rt], bf[ct], acc[rt][ct], 0, 0, 0);
        }
        __syncthreads();
    }

#pragma unroll
    for (int rt = 0; rt < 4; ++rt)
#pragma unroll
        for (int ct = 0; ct < 2; ++ct) {
            int col = wcol + ct * 16 + fm;
            int row0 = m0 + rt * 16 + quad * 4;
            ushort4 o;
#pragma unroll
            for (int r = 0; r < 4; ++r) ((unsigned short*)&o)[r] = f2bf(acc[rt][ct][r]);
            *(ushort4*)&CtT[(size_t)col * N_NODES + row0] = o;
        }
}

// ---------------- head: relu(pooled@wfa+bfa) @ wfb + bfb ----------------

__global__ __launch_bounds__(128) void head(const float* __restrict__ pooled,
                                            const float* __restrict__ wfa,
                                            const float* __restrict__ bfa,
                                            const float* __restrict__ wfb,
                                            const float* __restrict__ bfb,
                                            float* __restrict__ out) {
    int g = blockIdx.x;
    int f = threadIdx.x;
    __shared__ float pl[128];
    pl[f] = pooled[g * 128 + f];
    __syncthreads();
    float a = bfa[f];
    for (int k = 0; k < 128; ++k) a += pl[k] * wfa[k * 128 + f];
    float p2 = fmaxf(a, 0.f);
    __shared__ float o0[128], o1[128];
    o0[f] = p2 * wfb[f * 2 + 0];
    o1[f] = p2 * wfb[f * 2 + 1];
    __syncthreads();
    if (f == 0) {
        float a0 = bfb[0], a1 = bfb[1];
#pragma unroll
        for (int k = 0; k < 128; ++k) { a0 += o0[k]; a1 += o1[k]; }
        out[g * 2 + 0] = a0;
        out[g * 2 + 1] = a1;
    }
}

// ---------------- launch ----------------

extern "C" void kernel_launch(void* const* d_in, const int* in_sizes, int n_in,
                              void* d_out, int out_size, void* d_ws, size_t ws_size,
                              hipStream_t stream) {
    const float* x   = (const float*)d_in[0];
    const int* ei    = (const int*)d_in[1];
    const int* gid   = (const int*)d_in[3];
    const float* ge  = (const float*)d_in[4];
    const float* he  = (const float*)d_in[5];
    const float* wa[3] = {(const float*)d_in[6],  (const float*)d_in[12], (const float*)d_in[18]};
    const float* ba[3] = {(const float*)d_in[7],  (const float*)d_in[13], (const float*)d_in[19]};
    const float* gg[3] = {(const float*)d_in[8],  (const float*)d_in[14], (const float*)d_in[20]};
    const float* bb_[3]= {(const float*)d_in[9],  (const float*)d_in[15], (const float*)d_in[21]};
    const float* wb[3] = {(const float*)d_in[10], (const float*)d_in[16], (const float*)d_in[22]};
    const float* bbias[3] = {(const float*)d_in[11], (const float*)d_in[17], (const float*)d_in[23]};
    const float* wfa = (const float*)d_in[24];
    const float* bfa = (const float*)d_in[25];
    const float* wfb = (const float*)d_in[26];
    const float* bfb = (const float*)d_in[27];
    float* out = (float*)d_out;

    char* ws = (char*)d_ws;
    size_t o = 0;
    auto alloc = [&](size_t bytes) { char* p = ws + o; o += (bytes + 255) & ~(size_t)255; return p; };
    unsigned short* tT = (unsigned short*)alloc((size_t)128 * N_NODES * 2 + 1024);
    unsigned short* z  = (unsigned short*)alloc((size_t)N_NODES * 128 * 2);
    unsigned char* Sb  = (unsigned char*)alloc((size_t)NB * S_ROWS * S_COLS2);
    float* pstat = (float*)alloc((3 * 2048 + 8192) * 4);   // [layer][psum|psq][8][128] + pooled[64][128]
    unsigned short* wt0  = (unsigned short*)alloc(128 * K0PAD * 2);
    unsigned short* wta1 = (unsigned short*)alloc(128 * 128 * 2);
    unsigned short* wta2 = (unsigned short*)alloc(128 * 128 * 2);
    unsigned short* wtb0 = (unsigned short*)alloc(128 * 128 * 2);
    unsigned short* wtb1 = (unsigned short*)alloc(128 * 128 * 2);
    unsigned short* wtb2 = (unsigned short*)alloc(128 * 128 * 2);
    (void)ws_size; (void)in_sizes; (void)n_in; (void)out_size;

    const int* esrc_in = ei;
    const int* edst_in = ei + NE;

    // prep grid: 256 build blocks + ceil((128*448 + 5*128*128)/256) = 544 transpose blocks
    prep<<<256 + 544, 256, 0, stream>>>(esrc_in, edst_in, Sb,
                                        wa[0], wa[1], wa[2], wb[0], wb[1], wb[2],
                                        wt0, wta1, wta2, wtb0, wtb1, wtb2, pstat);

    float* ps0 = pstat;            float* pq0 = pstat + 1024;
    float* ps1 = pstat + 2048;     float* pq1 = pstat + 3072;
    float* ps2 = pstat + 4096;     float* pq2 = pstat + 5120;
    float* pooled = pstat + 6144;

    // layer 0
    gemm_embed64<<<400, 256, 0, stream>>>(x, wt0, wa[0], gid, ge, he, tT);
    agg_mfma<<<NB * AGG_TILES, 256, 0, stream>>>(Sb, tT, ba[0], z, ps0, pq0);
    gemm_post64<MODE_FUSED><<<400, 256, 0, stream>>>(z, ps0, pq0, gg[0], bb_[0],
                                                     wtb0, bbias[0], wta1, tT, nullptr);
    // layer 1
    agg_mfma<<<NB * AGG_TILES, 256, 0, stream>>>(Sb, tT, ba[1], z, ps1, pq1);
    gemm_post64<MODE_FUSED><<<400, 256, 0, stream>>>(z, ps1, pq1, gg[1], bb_[1],
                                                     wtb1, bbias[1], wta2, tT, nullptr);
    // layer 2
    agg_mfma<<<NB * AGG_TILES, 256, 0, stream>>>(Sb, tT, ba[2], z, ps2, pq2);
    gemm_post64<MODE_FINAL><<<400, 256, 0, stream>>>(z, ps2, pq2, gg[2], bb_[2],
                                                     wtb2, bbias[2], nullptr, nullptr, pooled);

    head<<<NB, 128, 0, stream>>>(pooled, wfa, bfa, wfb, bfb, out);
}